// Round 10
// baseline (259.785 us; speedup 1.0000x reference)
//
#include <hip/hip_runtime.h>
#include <hip/hip_bf16.h>
#include <stdint.h>

// NeuralFSM as integer FSM (exact). R23:
//  - p4 re-sorts each FULL 256-edge block by dst-BANK ((w>>2)&31) and stores
//    that order directly (sigma dropped). mega's subword-j lane-set reads
//    stride-4 samples of the block -> ~2 edges/bank on the mask atomicOr
//    (2-way = free), attacking the measured 2840cy/CU-iter atomic-conflict
//    floor. Cost: sPk reads widen to the block's ~8 src bins (~3-4-way,
//    +~1Kcy, the known R14 pattern) - calibrated net win ~3-5us on mega.
//    mega is BYTE-IDENTICAL to R22 (any per-bucket permutation is correct).
//  - per-wave counting sort: 32 bins + 8KB scratch; p4 LDS 57->66.5KB,
//    still 2 blocks/CU; partial tail blocks stay identity.
//  - R22 kept: wave-shuffle scan in build, mask zeroing before reload asm,
//    byte-addr packed csr word, x4 edge loads, two-pass p4, s_sleep(1) spin,
//    fixed-capacity buckets + cursor reserve, fence-free 2-level grid
//    barrier, coherent x4 state reload.

#define NN 100000
#define EE 6400000
#define NCHARS 2048
#define ITERS 20

#define NBKT 250          // dst buckets == mega blocks
#define NPB 400           // nodes per bucket
#define WPS 12500         // words of packed state (NN/8)
#define X4N 3125          // WPS/4
#define CEDGE 12800       // edges per build block
#define NCHUNK 500        // build blocks
#define CAPB 27648        // fixed region capacity per bucket (mean 25600; 108*256)
#define HCAP 13824        // p4 half-bucket LDS cap

// ---- bar region (words; lines 64B apart); zeroed by hipMemsetAsync ----
#define MEG_TOP     2080
#define CUR_OFF     3328                // cursor/count[250]
#define BAR_WORDS   4096                // 16 KB

typedef uint32_t u32x4 __attribute__((ext_vector_type(4)));

__device__ inline void mega_barrier(uint32_t* bar, int line, uint32_t epoch) {
    __syncthreads();                      // drains vmcnt: prior ops at coherence pt
    if (threadIdx.x == 0) {
        uint32_t old = atomicAdd(&bar[1664 + line * 16], 1u);
        if (old + 1u == 10u * epoch) {
            uint32_t told = atomicAdd(&bar[MEG_TOP], 1u);
            if (told + 1u == 25u * epoch) {
                for (int r = 0; r < 25; ++r)
                    atomicExch(&bar[2112 + r * 16], epoch);
            }
        }
        while (__hip_atomic_load(&bar[2112 + line * 16], __ATOMIC_RELAXED,
                                 __HIP_MEMORY_SCOPE_AGENT) < epoch)
            __builtin_amdgcn_s_sleep(1);
    }
    __syncthreads();
}

// ---------- build: decode-stripe + count + reserve + scatter + lut write ----------
__global__ void __launch_bounds__(512) build_kernel(const int* __restrict__ src,
                                                    const int* __restrict__ dst,
                                                    const float* __restrict__ s0,
                                                    const float* __restrict__ T,
                                                    uint32_t* __restrict__ gPk0,
                                                    uint8_t* __restrict__ nextT,
                                                    uint32_t* __restrict__ csr,
                                                    uint32_t* __restrict__ bar) {
    __shared__ uint32_t stage[CEDGE];       // 51.2 KB
    __shared__ uint32_t cw[8][256];         // 8 KB: per-wave counts -> cursors
    __shared__ uint32_t scanb[512];
    __shared__ uint32_t loc[NBKT + 1];
    __shared__ uint32_t segoff[NBKT];
    __shared__ uint8_t  lut[CEDGE];         // 12.8 KB slot->bucket
    int t = threadIdx.x, w = t >> 6;
    int c = blockIdx.x;
    int e0 = c * CEDGE;
    const int4* ps4 = (const int4*)(src + e0);
    const int4* pd4 = (const int4*)(dst + e0);
    uint32_t* cursorG = bar + CUR_OFF;

    // --- decode stripe: block c packs nodes [c*200, c*200+200) -> 25 words ---
    if (t < 25) loc[t] = 0;
    __syncthreads();
    if (t < 200) {
        const float* row = s0 + ((size_t)c * 200 + t) * 8;
        int s = 0;
        #pragma unroll
        for (int q = 1; q < 8; ++q) if (row[q] > 0.5f) s = q;
        atomicOr(&loc[t >> 3], (uint32_t)s << ((t & 7) << 2));
    }
    __syncthreads();
    if (t < 25) gPk0[c * 25 + t] = loc[t];
    if (c < 4) {                             // nextT: 4 blocks x 512 entries
        const float* row = T + (c * 512 + t) * 8;
        int s = 0;
        #pragma unroll
        for (int q = 1; q < 8; ++q) if (row[q] > 0.5f) s = q;
        nextT[c * 512 + t] = (uint8_t)s;
    }
    __syncthreads();

    // --- count (int4 groups; edge group 4i..4i+3 -> wave (i%512)>>6) ---
    for (int i = t; i < 8 * 256; i += 512) ((uint32_t*)cw)[i] = 0;
    __syncthreads();
    for (int i = t; i < CEDGE / 4; i += 512) {
        int4 d = pd4[i];
        atomicAdd(&cw[w][d.x / NPB], 1u);
        atomicAdd(&cw[w][d.y / NPB], 1u);
        atomicAdd(&cw[w][d.z / NPB], 1u);
        atomicAdd(&cw[w][d.w / NPB], 1u);
    }
    __syncthreads();
    uint32_t tot = 0;
    if (t < NBKT) {
        #pragma unroll
        for (int w2 = 0; w2 < 8; ++w2) tot += cw[w2][t];
    }
    // wave-shuffle exclusive scan over 512 threads (3 barriers)
    uint32_t x = tot;
    #pragma unroll
    for (int off = 1; off < 64; off <<= 1) {
        uint32_t y = __shfl_up(x, off, 64);
        if ((t & 63) >= off) x += y;
    }
    if ((t & 63) == 63) scanb[t >> 6] = x;   // per-wave total
    __syncthreads();
    if (t < 8) {
        uint32_t v = scanb[t];
        #pragma unroll
        for (int off = 1; off < 8; off <<= 1) {
            uint32_t y = __shfl_up(v, off, 8);
            if (t >= off) v += y;
        }
        scanb[t] = v;                        // inclusive wave-total prefix
    }
    __syncthreads();
    uint32_t incl = x + ((t >> 6) ? scanb[(t >> 6) - 1] : 0u);
    if (t < NBKT) {
        uint32_t excl = incl - tot;
        loc[t] = excl;
        uint32_t myStart = atomicAdd(&cursorG[t], tot);   // reserve slice
        segoff[t] = (uint32_t)t * CAPB + myStart - excl;
        uint32_t acc = excl;                 // counts -> per-wave stage cursors
        #pragma unroll
        for (int w2 = 0; w2 < 8; ++w2) {
            uint32_t cv = cw[w2][t];
            cw[w2][t] = acc;
            acc += cv;
        }
    }
    if (t == 0) loc[NBKT] = CEDGE;
    __syncthreads();
    // lut fill: thread b writes its own disjoint range
    for (int b = t; b < NBKT; b += 512) {
        uint32_t lo = loc[b], hi = loc[b + 1];
        for (uint32_t i = lo; i < hi; ++i) lut[i] = (uint8_t)b;
    }
    // scatter (IDENTICAL int4-group wave mapping as count phase)
    // pack: [31:18]=src>>3, [15:13]=src&7, [10:2]=dl*4
    //  -> wv>>16 = LDS byte addr of packed word; (wv>>11)&31 = nibble shift
    for (int i = t; i < CEDGE / 4; i += 512) {
        int4 d = pd4[i];
        int4 s = ps4[i];
        int bb; uint32_t dl, pos;
        bb = d.x / NPB; dl = (uint32_t)(d.x - bb * NPB);
        pos = atomicAdd(&cw[w][bb], 1u);
        stage[pos] = ((uint32_t)(s.x >> 3) << 18) | ((uint32_t)(s.x & 7) << 13) | (dl << 2);
        bb = d.y / NPB; dl = (uint32_t)(d.y - bb * NPB);
        pos = atomicAdd(&cw[w][bb], 1u);
        stage[pos] = ((uint32_t)(s.y >> 3) << 18) | ((uint32_t)(s.y & 7) << 13) | (dl << 2);
        bb = d.z / NPB; dl = (uint32_t)(d.z - bb * NPB);
        pos = atomicAdd(&cw[w][bb], 1u);
        stage[pos] = ((uint32_t)(s.z >> 3) << 18) | ((uint32_t)(s.z & 7) << 13) | (dl << 2);
        bb = d.w / NPB; dl = (uint32_t)(d.w - bb * NPB);
        pos = atomicAdd(&cw[w][bb], 1u);
        stage[pos] = ((uint32_t)(s.w >> 3) << 18) | ((uint32_t)(s.w & 7) << 13) | (dl << 2);
    }
    __syncthreads();
    // coalesced write via lut (2 LDS reads instead of 9-step binary search)
    for (int i = t; i < CEDGE; i += 512) {
        csr[segoff[lut[i]] + (uint32_t)i] = stage[i];
    }
}

// ---------- P4: src>>8 bin-sort + per-256-block dst-bank re-sort ----------
// Pass A histograms csr directly; pass B scatters into ob (src-sorted).
// Then each FULL 256-block is counting-sorted by dst-bank ((w>>2)&31) by one
// wave and written back coalesced (identity position). mega's stride-4
// subword sampling then sees ~2 edges/bank on mask atomics (free).
__global__ void __launch_bounds__(512) p4_sortsrc(uint32_t* __restrict__ csr,
                                                  const uint32_t* __restrict__ cntG) {
    __shared__ uint32_t ob[HCAP];           // 55.3 KB
    __shared__ uint32_t binh[512];          // 2 KB
    __shared__ uint32_t wbin[8 * 32];       // 1 KB per-wave bank bins
    __shared__ uint32_t wscr[8 * 256];      // 8 KB per-wave sort scratch
    int t = threadIdx.x;
    int j = blockIdx.x;
    int b = j >> 1, h = j & 1;
    uint32_t n  = cntG[b];
    uint32_t n1 = (((n + 1) >> 1) + 255u) & ~255u;   // split rounded UP to 256
    if (n1 > n) n1 = n;
    uint32_t r0 = (uint32_t)b * CAPB + (h ? n1 : 0); // 256-aligned (CAPB=108*256)
    uint32_t cnt = h ? n - n1 : n1;
    if (cnt == 0 || cnt > HCAP) return;     // leave unsorted (still correct)
    binh[t] = 0;
    __syncthreads();
    for (uint32_t i = t; i < cnt; i += 512) atomicAdd(&binh[csr[r0 + i] >> 23], 1u);  // src>>8
    __syncthreads();
    uint32_t v = binh[t];
    __syncthreads();
    for (int off = 1; off < 512; off <<= 1) {
        uint32_t x = (t >= off) ? binh[t - off] : 0u;
        __syncthreads();
        binh[t] += x;
        __syncthreads();
    }
    uint32_t excl = binh[t] - v;
    __syncthreads();
    binh[t] = excl;                          // becomes cursor
    __syncthreads();
    for (uint32_t i = t; i < cnt; i += 512) {
        uint32_t w = csr[r0 + i];            // second read (L2-resident)
        uint32_t pos = atomicAdd(&binh[w >> 23], 1u);
        ob[pos] = w;                         // LDS scatter (src-sorted order)
    }
    __syncthreads();
    // per-256-block dst-bank counting sort (one wave per block, round-robin);
    // any within-block permutation is correct (multiset preserved).
    {
        uint32_t nf = cnt >> 8;              // full 256-blocks
        int wv = t >> 6, ln = t & 63;
        uint32_t* bb = wbin + wv * 32;
        uint32_t* sc = wscr + wv * 256;
        for (uint32_t B = (uint32_t)wv; B < nf; B += 8) {
            uint32_t base_ = B << 8;
            u32x4 ed = *(const u32x4*)(ob + base_ + (ln << 2));
            if (ln < 32) bb[ln] = 0;
            atomicAdd(&bb[(ed.x >> 2) & 31u], 1u);
            atomicAdd(&bb[(ed.y >> 2) & 31u], 1u);
            atomicAdd(&bb[(ed.z >> 2) & 31u], 1u);
            atomicAdd(&bb[(ed.w >> 2) & 31u], 1u);
            uint32_t c_ = (ln < 32) ? bb[ln] : 0u;
            uint32_t s_ = c_;
            #pragma unroll
            for (int off = 1; off < 32; off <<= 1) {
                uint32_t y = __shfl_up(s_, off, 64);
                if (ln >= off && ln < 32) s_ += y;
            }
            if (ln < 32) bb[ln] = s_ - c_;   // exclusive -> cursor
            uint32_t p0 = atomicAdd(&bb[(ed.x >> 2) & 31u], 1u); sc[p0] = ed.x;
            uint32_t p1 = atomicAdd(&bb[(ed.y >> 2) & 31u], 1u); sc[p1] = ed.y;
            uint32_t p2 = atomicAdd(&bb[(ed.z >> 2) & 31u], 1u); sc[p2] = ed.z;
            uint32_t p3 = atomicAdd(&bb[(ed.w >> 2) & 31u], 1u); sc[p3] = ed.w;
            *(u32x4*)(csr + r0 + base_ + (ln << 2)) = *(const u32x4*)(sc + (ln << 2));
        }
        // partial tail block: identity writeback
        for (uint32_t i = (nf << 8) + (uint32_t)t; i < cnt; i += 512)
            csr[r0 + i] = ob[i];
    }
}

// ---------- mega: fence-free persistent 20 iterations (R22 verbatim) ----------
__global__ void __launch_bounds__(1024) mega_kernel(const uint32_t* __restrict__ csr,
                                                    uint32_t* __restrict__ gPkA,
                                                    uint32_t* __restrict__ gPkB,
                                                    const uint8_t* __restrict__ nextT,
                                                    float* __restrict__ out,
                                                    uint32_t* __restrict__ bar) {
    __shared__ uint32_t sPk[WPS];           // 50 KB packed state
    __shared__ uint32_t mask[NPB];          // 1.6 KB
    __shared__ uint32_t packOwn[NPB / 8];
    __shared__ uint8_t  nT[NCHARS];
    __shared__ uint8_t  sown[NPB];
    int t = threadIdx.x;
    int b = blockIdx.x;
    uint32_t base = (uint32_t)b * CAPB;
    uint32_t end  = base + bar[CUR_OFF + b];     // bucket count (kernel-boundary coherent)

    if (t < 512) ((uint32_t*)nT)[t] = ((const uint32_t*)nextT)[t];   // 2048 B
    const int line = b % 25;

    for (int p = 0; p < ITERS; ++p) {
        const uint32_t* curG = (p & 1) ? gPkB : gPkA;
        uint32_t*       nxtG = (p & 1) ? gPkA : gPkB;
        // LDS zeroing first: ds_writes issue under the global-load latency
        if (t < NPB) mask[t] = 0;
        if (t < NPB / 8) packOwn[t] = 0;
        // coherent x4 reload of full packed state (bypasses stale L1/L2)
        {
            const u32x4* g4 = (const u32x4*)curG;
            int i0 = t, i1 = t + 1024, i2 = t + 2048;
            int i3 = t + 3072; if (i3 > X4N - 1) i3 = X4N - 1;
            const u32x4 *p0 = g4 + i0, *p1 = g4 + i1, *p2 = g4 + i2, *p3 = g4 + i3;
            u32x4 a0, a1, a2, a3;
            asm volatile(
                "global_load_dwordx4 %0, %4, off sc1\n\t"
                "global_load_dwordx4 %1, %5, off sc1\n\t"
                "global_load_dwordx4 %2, %6, off sc1\n\t"
                "global_load_dwordx4 %3, %7, off sc1\n\t"
                "s_waitcnt vmcnt(0)"
                : "=&v"(a0), "=&v"(a1), "=&v"(a2), "=&v"(a3)
                : "v"(p0), "v"(p1), "v"(p2), "v"(p3)
                : "memory");
            u32x4* s4 = (u32x4*)sPk;
            s4[i0] = a0; s4[i1] = a1; s4[i2] = a2; s4[i3] = a3;
        }
        __syncthreads();

        // gather: dst-bank-sorted 256-blocks -> subword j's stride-4 sample
        // set is bank-uniform on the mask atomics (~2/bank = free)
        auto edge1 = [&](uint32_t wv) {
            uint32_t val = *(const uint32_t*)((const char*)sPk + (wv >> 16));
            uint32_t nb  = (val >> ((wv >> 11) & 31u)) & 7u;
            atomicOr((uint32_t*)((char*)mask + (wv & 0x7FCu)), 1u << nb);
        };
        uint32_t e = base + ((uint32_t)t << 2);
        for (; e + 4099 < end; e += 8192) {
            u32x4 wa = *(const u32x4*)(csr + e);
            u32x4 wb = *(const u32x4*)(csr + e + 4096);
            edge1(wa.x); edge1(wa.y); edge1(wa.z); edge1(wa.w);
            edge1(wb.x); edge1(wb.y); edge1(wb.z); edge1(wb.w);
        }
        for (; e + 3 < end; e += 4096) {
            u32x4 wa = *(const u32x4*)(csr + e);
            edge1(wa.x); edge1(wa.y); edge1(wa.z); edge1(wa.w);
        }
        for (; e < end; ++e) {
            edge1(csr[e]);
        }
        __syncthreads();

        // own-node update + nibble pack
        if (t < NPB) {
            int node = b * NPB + t;
            uint32_t sOwn = (sPk[node >> 3] >> ((node & 7) << 2)) & 7u;
            uint8_t ns = nT[(mask[t] << 3) + sOwn];
            sown[t] = ns;
            atomicOr(&packOwn[t >> 3], (uint32_t)ns << ((t & 7) << 2));
        }
        __syncthreads();
        if (p < ITERS - 1) {
            if (t < NPB / 8)
                __hip_atomic_store(&nxtG[(NPB / 8) * b + t], packOwn[t],
                                   __ATOMIC_RELAXED, __HIP_MEMORY_SCOPE_AGENT);
            mega_barrier(bar, line, (uint32_t)(p + 1));
        }
    }
    __syncthreads();
    // one-hot output: 400 nodes * 8 floats, coalesced
    for (int f = t; f < NPB * 8; f += 1024) {
        int node = f >> 3;
        out[(size_t)b * (NPB * 8) + f] = ((f & 7) == (int)sown[node]) ? 1.f : 0.f;
    }
}

// ---------- fallback (tiny ws): R1 mask/atomicOr path ----------
__global__ void fb_decode(const float* __restrict__ s0, const float* __restrict__ T,
                          uint8_t* __restrict__ state, uint8_t* __restrict__ nextT,
                          uint32_t* __restrict__ mask) {
    int i = blockIdx.x * blockDim.x + threadIdx.x;
    if (i < NCHARS) {
        const float* row = T + i * 8;
        int t = 0;
        #pragma unroll
        for (int k = 1; k < 8; ++k) if (row[k] > 0.5f) t = k;
        nextT[i] = (uint8_t)t;
    }
    if (i < NN) {
        const float* row = s0 + i * 8;
        int s = 0;
        #pragma unroll
        for (int k = 1; k < 8; ++k) if (row[k] > 0.5f) s = k;
        state[i] = (uint8_t)s;
        mask[i] = 0u;
    }
}
__global__ void fb_edge(const int* __restrict__ src, const int* __restrict__ dst,
                        const uint8_t* __restrict__ state, uint32_t* __restrict__ mask) {
    int i = blockIdx.x * blockDim.x + threadIdx.x;
    int stride = gridDim.x * blockDim.x;
    for (int e = i; e < EE; e += stride) atomicOr(&mask[dst[e]], 1u << state[src[e]]);
}
__global__ void fb_update(uint8_t* __restrict__ state, uint32_t* __restrict__ mask,
                          const uint8_t* __restrict__ nextT) {
    int i = blockIdx.x * blockDim.x + threadIdx.x;
    if (i < NN) {
        uint32_t m = mask[i];
        state[i] = nextT[(m << 3) + state[i]];
        mask[i] = 0u;
    }
}
__global__ void fb_output(const uint8_t* __restrict__ state, float* __restrict__ out) {
    int i = blockIdx.x * blockDim.x + threadIdx.x;
    if (i < NN) {
        int s = state[i];
        float4 lo = make_float4(s == 0 ? 1.f : 0.f, s == 1 ? 1.f : 0.f,
                                s == 2 ? 1.f : 0.f, s == 3 ? 1.f : 0.f);
        float4 hi = make_float4(s == 4 ? 1.f : 0.f, s == 5 ? 1.f : 0.f,
                                s == 6 ? 1.f : 0.f, s == 7 ? 1.f : 0.f);
        float4* o = (float4*)(out + (size_t)i * 8);
        o[0] = lo;
        o[1] = hi;
    }
}

extern "C" void kernel_launch(void* const* d_in, const int* in_sizes, int n_in,
                              void* d_out, int out_size, void* d_ws, size_t ws_size,
                              hipStream_t stream) {
    const float* s0  = (const float*)d_in[0];
    const int*   ei  = (const int*)d_in[1];   // [2,E]: row0=src, row1=dst
    const float* T   = (const float*)d_in[2];
    float*       out = (float*)d_out;
    const int* src = ei;
    const int* dst = ei + EE;

    uint8_t* basep = (uint8_t*)d_ws;
    size_t off = 0;
    auto alloc = [&](size_t sz) -> void* {
        void* p = basep + off;
        off += (sz + 255) & ~(size_t)255;
        return p;
    };
    uint32_t* csr   = (uint32_t*)alloc(sizeof(uint32_t) * (size_t)NBKT * CAPB);
    uint8_t*  nextT = (uint8_t*)alloc(NCHARS);
    uint32_t* gPkA  = (uint32_t*)alloc(sizeof(uint32_t) * WPS);
    uint32_t* gPkB  = (uint32_t*)alloc(sizeof(uint32_t) * WPS);
    uint32_t* bar   = (uint32_t*)alloc(sizeof(uint32_t) * BAR_WORDS);
    bool have_ws = (off <= ws_size);

    if (have_ws) {
        hipMemsetAsync(bar, 0, sizeof(uint32_t) * BAR_WORDS, stream);
        build_kernel<<<NCHUNK, 512, 0, stream>>>(src, dst, s0, T, gPkA, nextT, csr, bar);
        p4_sortsrc<<<NBKT * 2, 512, 0, stream>>>(csr, bar + CUR_OFF);
        mega_kernel<<<NBKT, 1024, 0, stream>>>(csr, gPkA, gPkB, nextT, out, bar);
    } else {
        uint32_t* mask = (uint32_t*)d_ws;           // < 1 MB path
        uint8_t*  nT   = (uint8_t*)d_ws + 400128;
        uint8_t*  st   = (uint8_t*)d_ws + 402432;
        fb_decode<<<391, 256, 0, stream>>>(s0, T, st, nT, mask);
        for (int it = 0; it < ITERS; ++it) {
            fb_edge<<<2048, 256, 0, stream>>>(src, dst, st, mask);
            fb_update<<<391, 256, 0, stream>>>(st, mask, nT);
        }
        fb_output<<<391, 256, 0, stream>>>(st, out);
    }
}

// Round 11
// 245.624 us; speedup vs baseline: 1.0577x; 1.0577x over previous
//
#include <hip/hip_runtime.h>
#include <hip/hip_bf16.h>
#include <stdint.h>

// NeuralFSM as integer FSM (exact). R24 = R22 verbatim (final form):
//  - R23's per-256-block dst-bank re-sort REVERTED: it broke the sigma
//    property (conflicts 1.42e7 -> 1.88e7, mega +8us). src-locality of the
//    subword lane-sets is worth more than dst-bank uniformity; the sigma
//    layout is the joint optimum of the tested layouts.
//  - Session ledger: R14 dwordx4 gather (-5us), R15 sigma permutation (-4us),
//    R20 two-pass p4 (-2us), R22 micro-opts (~0). Five structural attempts on
//    mega's gather/sync/layout (R17 run-accum, R18 transpose-runs, R19
//    line-pipelined exchange, R21 2x block split, R23 bank-sort) all
//    regressed or hung. mega = 117.5us, non-mega ~130us constant.
//  - Structure: build (decode + count + cursor-reserve into fixed-capacity
//    buckets + lut scatter), p4 (two-pass src>>8 bin-sort per half-bucket,
//    sigma-permuted coalesced writeback), mega (persistent, 20 iters,
//    fence-free 2-level grid barrier, coherent x4 state reload, x4 edge
//    loads, per-edge LDS atomicOr with conflict-free sPk reads).

#define NN 100000
#define EE 6400000
#define NCHARS 2048
#define ITERS 20

#define NBKT 250          // dst buckets == mega blocks
#define NPB 400           // nodes per bucket
#define WPS 12500         // words of packed state (NN/8)
#define X4N 3125          // WPS/4
#define CEDGE 12800       // edges per build block
#define NCHUNK 500        // build blocks
#define CAPB 27648        // fixed region capacity per bucket (mean 25600; 108*256)
#define HCAP 13824        // p4 half-bucket LDS cap

// ---- bar region (words; lines 64B apart); zeroed by hipMemsetAsync ----
#define MEG_TOP     2080
#define CUR_OFF     3328                // cursor/count[250]
#define BAR_WORDS   4096                // 16 KB

typedef uint32_t u32x4 __attribute__((ext_vector_type(4)));

__device__ inline void mega_barrier(uint32_t* bar, int line, uint32_t epoch) {
    __syncthreads();                      // drains vmcnt: prior ops at coherence pt
    if (threadIdx.x == 0) {
        uint32_t old = atomicAdd(&bar[1664 + line * 16], 1u);
        if (old + 1u == 10u * epoch) {
            uint32_t told = atomicAdd(&bar[MEG_TOP], 1u);
            if (told + 1u == 25u * epoch) {
                for (int r = 0; r < 25; ++r)
                    atomicExch(&bar[2112 + r * 16], epoch);
            }
        }
        while (__hip_atomic_load(&bar[2112 + line * 16], __ATOMIC_RELAXED,
                                 __HIP_MEMORY_SCOPE_AGENT) < epoch)
            __builtin_amdgcn_s_sleep(1);
    }
    __syncthreads();
}

// ---------- build: decode-stripe + count + reserve + scatter + lut write ----------
__global__ void __launch_bounds__(512) build_kernel(const int* __restrict__ src,
                                                    const int* __restrict__ dst,
                                                    const float* __restrict__ s0,
                                                    const float* __restrict__ T,
                                                    uint32_t* __restrict__ gPk0,
                                                    uint8_t* __restrict__ nextT,
                                                    uint32_t* __restrict__ csr,
                                                    uint32_t* __restrict__ bar) {
    __shared__ uint32_t stage[CEDGE];       // 51.2 KB
    __shared__ uint32_t cw[8][256];         // 8 KB: per-wave counts -> cursors
    __shared__ uint32_t scanb[512];
    __shared__ uint32_t loc[NBKT + 1];
    __shared__ uint32_t segoff[NBKT];
    __shared__ uint8_t  lut[CEDGE];         // 12.8 KB slot->bucket
    int t = threadIdx.x, w = t >> 6;
    int c = blockIdx.x;
    int e0 = c * CEDGE;
    const int4* ps4 = (const int4*)(src + e0);
    const int4* pd4 = (const int4*)(dst + e0);
    uint32_t* cursorG = bar + CUR_OFF;

    // --- decode stripe: block c packs nodes [c*200, c*200+200) -> 25 words ---
    if (t < 25) loc[t] = 0;
    __syncthreads();
    if (t < 200) {
        const float* row = s0 + ((size_t)c * 200 + t) * 8;
        int s = 0;
        #pragma unroll
        for (int q = 1; q < 8; ++q) if (row[q] > 0.5f) s = q;
        atomicOr(&loc[t >> 3], (uint32_t)s << ((t & 7) << 2));
    }
    __syncthreads();
    if (t < 25) gPk0[c * 25 + t] = loc[t];
    if (c < 4) {                             // nextT: 4 blocks x 512 entries
        const float* row = T + (c * 512 + t) * 8;
        int s = 0;
        #pragma unroll
        for (int q = 1; q < 8; ++q) if (row[q] > 0.5f) s = q;
        nextT[c * 512 + t] = (uint8_t)s;
    }
    __syncthreads();

    // --- count (int4 groups; edge group 4i..4i+3 -> wave (i%512)>>6) ---
    for (int i = t; i < 8 * 256; i += 512) ((uint32_t*)cw)[i] = 0;
    __syncthreads();
    for (int i = t; i < CEDGE / 4; i += 512) {
        int4 d = pd4[i];
        atomicAdd(&cw[w][d.x / NPB], 1u);
        atomicAdd(&cw[w][d.y / NPB], 1u);
        atomicAdd(&cw[w][d.z / NPB], 1u);
        atomicAdd(&cw[w][d.w / NPB], 1u);
    }
    __syncthreads();
    uint32_t tot = 0;
    if (t < NBKT) {
        #pragma unroll
        for (int w2 = 0; w2 < 8; ++w2) tot += cw[w2][t];
    }
    // wave-shuffle exclusive scan over 512 threads (3 barriers)
    uint32_t x = tot;
    #pragma unroll
    for (int off = 1; off < 64; off <<= 1) {
        uint32_t y = __shfl_up(x, off, 64);
        if ((t & 63) >= off) x += y;
    }
    if ((t & 63) == 63) scanb[t >> 6] = x;   // per-wave total
    __syncthreads();
    if (t < 8) {
        uint32_t v = scanb[t];
        #pragma unroll
        for (int off = 1; off < 8; off <<= 1) {
            uint32_t y = __shfl_up(v, off, 8);
            if (t >= off) v += y;
        }
        scanb[t] = v;                        // inclusive wave-total prefix
    }
    __syncthreads();
    uint32_t incl = x + ((t >> 6) ? scanb[(t >> 6) - 1] : 0u);
    if (t < NBKT) {
        uint32_t excl = incl - tot;
        loc[t] = excl;
        uint32_t myStart = atomicAdd(&cursorG[t], tot);   // reserve slice
        segoff[t] = (uint32_t)t * CAPB + myStart - excl;
        uint32_t acc = excl;                 // counts -> per-wave stage cursors
        #pragma unroll
        for (int w2 = 0; w2 < 8; ++w2) {
            uint32_t cv = cw[w2][t];
            cw[w2][t] = acc;
            acc += cv;
        }
    }
    if (t == 0) loc[NBKT] = CEDGE;
    __syncthreads();
    // lut fill: thread b writes its own disjoint range
    for (int b = t; b < NBKT; b += 512) {
        uint32_t lo = loc[b], hi = loc[b + 1];
        for (uint32_t i = lo; i < hi; ++i) lut[i] = (uint8_t)b;
    }
    // scatter (IDENTICAL int4-group wave mapping as count phase)
    // pack: [31:18]=src>>3, [15:13]=src&7, [10:2]=dl*4
    //  -> wv>>16 = LDS byte addr of packed word; (wv>>11)&31 = nibble shift
    for (int i = t; i < CEDGE / 4; i += 512) {
        int4 d = pd4[i];
        int4 s = ps4[i];
        int bb; uint32_t dl, pos;
        bb = d.x / NPB; dl = (uint32_t)(d.x - bb * NPB);
        pos = atomicAdd(&cw[w][bb], 1u);
        stage[pos] = ((uint32_t)(s.x >> 3) << 18) | ((uint32_t)(s.x & 7) << 13) | (dl << 2);
        bb = d.y / NPB; dl = (uint32_t)(d.y - bb * NPB);
        pos = atomicAdd(&cw[w][bb], 1u);
        stage[pos] = ((uint32_t)(s.y >> 3) << 18) | ((uint32_t)(s.y & 7) << 13) | (dl << 2);
        bb = d.z / NPB; dl = (uint32_t)(d.z - bb * NPB);
        pos = atomicAdd(&cw[w][bb], 1u);
        stage[pos] = ((uint32_t)(s.z >> 3) << 18) | ((uint32_t)(s.z & 7) << 13) | (dl << 2);
        bb = d.w / NPB; dl = (uint32_t)(d.w - bb * NPB);
        pos = atomicAdd(&cw[w][bb], 1u);
        stage[pos] = ((uint32_t)(s.w >> 3) << 18) | ((uint32_t)(s.w & 7) << 13) | (dl << 2);
    }
    __syncthreads();
    // coalesced write via lut (2 LDS reads instead of 9-step binary search)
    for (int i = t; i < CEDGE; i += 512) {
        csr[segoff[lut[i]] + (uint32_t)i] = stage[i];
    }
}

// ---------- P4: bin-sort each half-bucket by src>>8 (two-pass, ~57KB LDS) ----------
// Pass A histograms csr directly (no staging buffer); pass B re-reads csr
// (L2-resident) and scatters into ob. Writeback is coalesced and sigma-
// PERMUTED per 256-edge block so mega's x4 gather reads 64 consecutive
// sorted edges per subword window (2-way bank pattern = free).
__global__ void __launch_bounds__(512) p4_sortsrc(uint32_t* __restrict__ csr,
                                                  const uint32_t* __restrict__ cntG) {
    __shared__ uint32_t ob[HCAP];           // 55.3 KB
    __shared__ uint32_t binh[512];
    int t = threadIdx.x;
    int j = blockIdx.x;
    int b = j >> 1, h = j & 1;
    uint32_t n  = cntG[b];
    uint32_t n1 = (((n + 1) >> 1) + 255u) & ~255u;   // split rounded UP to 256
    if (n1 > n) n1 = n;
    uint32_t r0 = (uint32_t)b * CAPB + (h ? n1 : 0); // 256-aligned (CAPB=108*256)
    uint32_t cnt = h ? n - n1 : n1;
    if (cnt == 0 || cnt > HCAP) return;     // leave unsorted (still correct)
    binh[t] = 0;
    __syncthreads();
    for (uint32_t i = t; i < cnt; i += 512) atomicAdd(&binh[csr[r0 + i] >> 23], 1u);  // src>>8
    __syncthreads();
    uint32_t v = binh[t];
    __syncthreads();
    for (int off = 1; off < 512; off <<= 1) {
        uint32_t x = (t >= off) ? binh[t - off] : 0u;
        __syncthreads();
        binh[t] += x;
        __syncthreads();
    }
    uint32_t excl = binh[t] - v;
    __syncthreads();
    binh[t] = excl;                          // becomes cursor
    __syncthreads();
    for (uint32_t i = t; i < cnt; i += 512) {
        uint32_t w = csr[r0 + i];            // second read (L2-resident)
        uint32_t pos = atomicAdd(&binh[w >> 23], 1u);
        ob[pos] = w;                         // LDS scatter (sorted order)
    }
    __syncthreads();
    // coalesced permuted writeback: storage i <- sorted sigma(i) within each
    // FULL 256-block; identity on the partial tail block (any order correct).
    for (uint32_t i = t; i < cnt; i += 512) {
        uint32_t s = ((i | 255u) < cnt)
                   ? ((i & ~255u) | ((i & 3u) << 6) | ((i & 255u) >> 2))
                   : i;
        csr[r0 + i] = ob[s];
    }
}

// ---------- mega: fence-free persistent 20 iterations ----------
__global__ void __launch_bounds__(1024) mega_kernel(const uint32_t* __restrict__ csr,
                                                    uint32_t* __restrict__ gPkA,
                                                    uint32_t* __restrict__ gPkB,
                                                    const uint8_t* __restrict__ nextT,
                                                    float* __restrict__ out,
                                                    uint32_t* __restrict__ bar) {
    __shared__ uint32_t sPk[WPS];           // 50 KB packed state
    __shared__ uint32_t mask[NPB];          // 1.6 KB
    __shared__ uint32_t packOwn[NPB / 8];
    __shared__ uint8_t  nT[NCHARS];
    __shared__ uint8_t  sown[NPB];
    int t = threadIdx.x;
    int b = blockIdx.x;
    uint32_t base = (uint32_t)b * CAPB;
    uint32_t end  = base + bar[CUR_OFF + b];     // bucket count (kernel-boundary coherent)

    if (t < 512) ((uint32_t*)nT)[t] = ((const uint32_t*)nextT)[t];   // 2048 B
    const int line = b % 25;

    for (int p = 0; p < ITERS; ++p) {
        const uint32_t* curG = (p & 1) ? gPkB : gPkA;
        uint32_t*       nxtG = (p & 1) ? gPkA : gPkB;
        // LDS zeroing first: ds_writes issue under the global-load latency
        if (t < NPB) mask[t] = 0;
        if (t < NPB / 8) packOwn[t] = 0;
        // coherent x4 reload of full packed state (bypasses stale L1/L2)
        {
            const u32x4* g4 = (const u32x4*)curG;
            int i0 = t, i1 = t + 1024, i2 = t + 2048;
            int i3 = t + 3072; if (i3 > X4N - 1) i3 = X4N - 1;
            const u32x4 *p0 = g4 + i0, *p1 = g4 + i1, *p2 = g4 + i2, *p3 = g4 + i3;
            u32x4 a0, a1, a2, a3;
            asm volatile(
                "global_load_dwordx4 %0, %4, off sc1\n\t"
                "global_load_dwordx4 %1, %5, off sc1\n\t"
                "global_load_dwordx4 %2, %6, off sc1\n\t"
                "global_load_dwordx4 %3, %7, off sc1\n\t"
                "s_waitcnt vmcnt(0)"
                : "=&v"(a0), "=&v"(a1), "=&v"(a2), "=&v"(a3)
                : "v"(p0), "v"(p1), "v"(p2), "v"(p3)
                : "memory");
            u32x4* s4 = (u32x4*)sPk;
            s4[i0] = a0; s4[i1] = a1; s4[i2] = a2; s4[i3] = a3;
        }
        __syncthreads();

        // gather: sigma-permuted storage -> subword j across the wave covers
        // 64 consecutive sorted edges (one src>>8 bin -> conflict-free)
        auto edge1 = [&](uint32_t wv) {
            uint32_t val = *(const uint32_t*)((const char*)sPk + (wv >> 16));
            uint32_t nb  = (val >> ((wv >> 11) & 31u)) & 7u;
            atomicOr((uint32_t*)((char*)mask + (wv & 0x7FCu)), 1u << nb);
        };
        uint32_t e = base + ((uint32_t)t << 2);
        for (; e + 4099 < end; e += 8192) {
            u32x4 wa = *(const u32x4*)(csr + e);
            u32x4 wb = *(const u32x4*)(csr + e + 4096);
            edge1(wa.x); edge1(wa.y); edge1(wa.z); edge1(wa.w);
            edge1(wb.x); edge1(wb.y); edge1(wb.z); edge1(wb.w);
        }
        for (; e + 3 < end; e += 4096) {
            u32x4 wa = *(const u32x4*)(csr + e);
            edge1(wa.x); edge1(wa.y); edge1(wa.z); edge1(wa.w);
        }
        for (; e < end; ++e) {
            edge1(csr[e]);
        }
        __syncthreads();

        // own-node update + nibble pack
        if (t < NPB) {
            int node = b * NPB + t;
            uint32_t sOwn = (sPk[node >> 3] >> ((node & 7) << 2)) & 7u;
            uint8_t ns = nT[(mask[t] << 3) + sOwn];
            sown[t] = ns;
            atomicOr(&packOwn[t >> 3], (uint32_t)ns << ((t & 7) << 2));
        }
        __syncthreads();
        if (p < ITERS - 1) {
            if (t < NPB / 8)
                __hip_atomic_store(&nxtG[(NPB / 8) * b + t], packOwn[t],
                                   __ATOMIC_RELAXED, __HIP_MEMORY_SCOPE_AGENT);
            mega_barrier(bar, line, (uint32_t)(p + 1));
        }
    }
    __syncthreads();
    // one-hot output: 400 nodes * 8 floats, coalesced
    for (int f = t; f < NPB * 8; f += 1024) {
        int node = f >> 3;
        out[(size_t)b * (NPB * 8) + f] = ((f & 7) == (int)sown[node]) ? 1.f : 0.f;
    }
}

// ---------- fallback (tiny ws): R1 mask/atomicOr path ----------
__global__ void fb_decode(const float* __restrict__ s0, const float* __restrict__ T,
                          uint8_t* __restrict__ state, uint8_t* __restrict__ nextT,
                          uint32_t* __restrict__ mask) {
    int i = blockIdx.x * blockDim.x + threadIdx.x;
    if (i < NCHARS) {
        const float* row = T + i * 8;
        int t = 0;
        #pragma unroll
        for (int k = 1; k < 8; ++k) if (row[k] > 0.5f) t = k;
        nextT[i] = (uint8_t)t;
    }
    if (i < NN) {
        const float* row = s0 + i * 8;
        int s = 0;
        #pragma unroll
        for (int k = 1; k < 8; ++k) if (row[k] > 0.5f) s = k;
        state[i] = (uint8_t)s;
        mask[i] = 0u;
    }
}
__global__ void fb_edge(const int* __restrict__ src, const int* __restrict__ dst,
                        const uint8_t* __restrict__ state, uint32_t* __restrict__ mask) {
    int i = blockIdx.x * blockDim.x + threadIdx.x;
    int stride = gridDim.x * blockDim.x;
    for (int e = i; e < EE; e += stride) atomicOr(&mask[dst[e]], 1u << state[src[e]]);
}
__global__ void fb_update(uint8_t* __restrict__ state, uint32_t* __restrict__ mask,
                          const uint8_t* __restrict__ nextT) {
    int i = blockIdx.x * blockDim.x + threadIdx.x;
    if (i < NN) {
        uint32_t m = mask[i];
        state[i] = nextT[(m << 3) + state[i]];
        mask[i] = 0u;
    }
}
__global__ void fb_output(const uint8_t* __restrict__ state, float* __restrict__ out) {
    int i = blockIdx.x * blockDim.x + threadIdx.x;
    if (i < NN) {
        int s = state[i];
        float4 lo = make_float4(s == 0 ? 1.f : 0.f, s == 1 ? 1.f : 0.f,
                                s == 2 ? 1.f : 0.f, s == 3 ? 1.f : 0.f);
        float4 hi = make_float4(s == 4 ? 1.f : 0.f, s == 5 ? 1.f : 0.f,
                                s == 6 ? 1.f : 0.f, s == 7 ? 1.f : 0.f);
        float4* o = (float4*)(out + (size_t)i * 8);
        o[0] = lo;
        o[1] = hi;
    }
}

extern "C" void kernel_launch(void* const* d_in, const int* in_sizes, int n_in,
                              void* d_out, int out_size, void* d_ws, size_t ws_size,
                              hipStream_t stream) {
    const float* s0  = (const float*)d_in[0];
    const int*   ei  = (const int*)d_in[1];   // [2,E]: row0=src, row1=dst
    const float* T   = (const float*)d_in[2];
    float*       out = (float*)d_out;
    const int* src = ei;
    const int* dst = ei + EE;

    uint8_t* basep = (uint8_t*)d_ws;
    size_t off = 0;
    auto alloc = [&](size_t sz) -> void* {
        void* p = basep + off;
        off += (sz + 255) & ~(size_t)255;
        return p;
    };
    uint32_t* csr   = (uint32_t*)alloc(sizeof(uint32_t) * (size_t)NBKT * CAPB);
    uint8_t*  nextT = (uint8_t*)alloc(NCHARS);
    uint32_t* gPkA  = (uint32_t*)alloc(sizeof(uint32_t) * WPS);
    uint32_t* gPkB  = (uint32_t*)alloc(sizeof(uint32_t) * WPS);
    uint32_t* bar   = (uint32_t*)alloc(sizeof(uint32_t) * BAR_WORDS);
    bool have_ws = (off <= ws_size);

    if (have_ws) {
        hipMemsetAsync(bar, 0, sizeof(uint32_t) * BAR_WORDS, stream);
        build_kernel<<<NCHUNK, 512, 0, stream>>>(src, dst, s0, T, gPkA, nextT, csr, bar);
        p4_sortsrc<<<NBKT * 2, 512, 0, stream>>>(csr, bar + CUR_OFF);
        mega_kernel<<<NBKT, 1024, 0, stream>>>(csr, gPkA, gPkB, nextT, out, bar);
    } else {
        uint32_t* mask = (uint32_t*)d_ws;           // < 1 MB path
        uint8_t*  nT   = (uint8_t*)d_ws + 400128;
        uint8_t*  st   = (uint8_t*)d_ws + 402432;
        fb_decode<<<391, 256, 0, stream>>>(s0, T, st, nT, mask);
        for (int it = 0; it < ITERS; ++it) {
            fb_edge<<<2048, 256, 0, stream>>>(src, dst, st, mask);
            fb_update<<<391, 256, 0, stream>>>(st, mask, nT);
        }
        fb_output<<<391, 256, 0, stream>>>(st, out);
    }
}